// Round 2
// baseline (380.880 us; speedup 1.0000x reference)
//
#include <hip/hip_runtime.h>
#include <hip/hip_bf16.h>

// ---------------------------------------------------------------------------
// concat(x1,x2) -> LSTM(551->128, T=5) -> MLP 640->531->256->64->2 -> softmax
// B=16384, T=5, IN=551, H=128. bf16 MFMA 16x16x32, fp32 accum.
// R4: k1 rebuilt on the T3+T4 counted-vmcnt template (1 block/CU, raw
//     s_barrier, loads 2 K-steps ahead, vmcnt(6) never 0 in-loop):
//     - BM=128 (8 mt/wave, acc in 128 AGPRs) halves per-CU L2 W-traffic
//     - W staged via global_load_lds into 3 LDS buffers (wave-private tiles)
//     - x staged to regs (branchless single-load addressing -> exact vmcnt
//       counts), cvt fp32->bf16, ds_write into 2 A buffers
//     - uniform 6 VMEM issues/iter so s_waitcnt vmcnt(6) is exact
// Packed B/A-tile layout: 16(n|m) x 32(k) tile = 512 elems, element
//   (n,k) -> tile(tn=n>>4, tk=k>>5) at offset lane*8+j, lane=((k>>3)&3)*16+(n&15), j=k&7.
// Packed C-tile layout: 16x16 tile = 256 elems, (m,n) -> offset lane*4+r,
//   lane=((m>>2)&3)*16+(n&15), r=m&3.   (matches MFMA C layout per lane)
// ---------------------------------------------------------------------------

typedef short  short8  __attribute__((ext_vector_type(8)));
typedef short  short4v __attribute__((ext_vector_type(4)));
typedef float  f32x4   __attribute__((ext_vector_type(4)));

#define MFMA(a, b, c) __builtin_amdgcn_mfma_f32_16x16x32_bf16((a), (b), (c), 0, 0, 0)
#define WAITV(N) asm volatile("s_waitcnt vmcnt(" #N ")" ::: "memory")
#define MEMF()   asm volatile("" ::: "memory")
#define BAR()    __builtin_amdgcn_s_barrier()

__device__ __forceinline__ short f2bs(float f) {
    __hip_bfloat16 h = __float2bfloat16(f);   // RNE
    union { __hip_bfloat16 h; short s; } u; u.h = h; return u.s;
}
__device__ __forceinline__ float b2f(short s) {
    union { unsigned u; float f; } v; v.u = ((unsigned)(unsigned short)s) << 16; return v.f;
}
__device__ __forceinline__ float sigf(float x)  { return 1.f / (1.f + __expf(-x)); }
__device__ __forceinline__ float mytanh(float x){ return 2.f / (1.f + __expf(-2.f * x)) - 1.f; }

// async global(16B) -> LDS, lane-linear dest
__device__ __forceinline__ void gload16(const short* g, short* l) {
    __builtin_amdgcn_global_load_lds(
        (const __attribute__((address_space(1))) void*)g,
        (__attribute__((address_space(3))) void*)l, 16, 0, 0);
}

// ---------------- constants ----------------
#define BB     16384
#define TT     5
#define F1     300
#define F2     251
#define INF    551
#define KP     576          // padded K for input GEMM (18 k-tiles)
#define G4     512
#define HH     128
#define FLAT   640          // T*H (20 k-tiles)
#define L1N    531
#define L1P    576
#define L1KP   544          // 17 k-tiles
#define L2N    256
#define L3N    64

// ws offsets (bytes)
#define O_WIH  0u
#define O_WHH  589824u
#define O_W1   720896u
#define O_W2   1458176u
#define O_W3   1736704u
#define O_BG   1769472u
#define O_B1   1771520u
#define O_XG   1773824u
#define O_HS   85659904u
#define WS_NEED 106631424u

// ---------------------------------------------------------------------------
// prep: weights fp32 -> bf16, packed in B-fragment tile order
// ---------------------------------------------------------------------------
__device__ __forceinline__ void pack_b(const float* __restrict__ W, short* __restrict__ dst,
                                       int i, int tpn, int Nsrc, int Ksrc, int ldw)
{
    int tile = i >> 9, rem = i & 511, lane = rem >> 3, jj = rem & 7;
    int tn = tile / tpn, tk = tile - tn * tpn;
    int n = tn * 16 + (lane & 15);
    int k = tk * 32 + (lane >> 4) * 8 + jj;
    float v = (n < Nsrc && k < Ksrc) ? W[n * ldw + k] : 0.f;
    dst[i] = f2bs(v);
}

__global__ void prep_kernel(
    const float* __restrict__ W_ih, const float* __restrict__ W_hh,
    const float* __restrict__ b_ih, const float* __restrict__ b_hh,
    const float* __restrict__ W1,   const float* __restrict__ b1,
    const float* __restrict__ W2,   const float* __restrict__ W3,
    short* __restrict__ Wihp, short* __restrict__ Whhp, float* __restrict__ biasg,
    short* __restrict__ W1p,  float* __restrict__ b1p,  short* __restrict__ W2p,
    short* __restrict__ W3p)
{
    const int N0 = G4 * KP;            // 294912
    const int N1 = N0 + G4 * HH;       // +65536
    const int N2 = N1 + L1P * FLAT;    // +368640
    const int N3 = N2 + L2N * L1KP;    // +139264
    const int N4 = N3 + L3N * L2N;     // +16384
    const int N5 = N4 + G4;
    const int N6 = N5 + L1P;
    const int stride = gridDim.x * blockDim.x;
    for (int i = blockIdx.x * blockDim.x + threadIdx.x; i < N6; i += stride) {
        if (i < N0)      pack_b(W_ih, Wihp, i,       18, G4,  INF, INF);
        else if (i < N1) pack_b(W_hh, Whhp, i - N0,   4, G4,  HH,  HH);
        else if (i < N2) pack_b(W1,   W1p,  i - N1,  20, L1N, FLAT, FLAT);
        else if (i < N3) pack_b(W2,   W2p,  i - N2,  17, L2N, L1N, L1N);
        else if (i < N4) pack_b(W3,   W3p,  i - N3,   8, L3N, L2N, L2N);
        else if (i < N5) { int j = i - N4; biasg[j] = b_ih[j] + b_hh[j]; }
        else             { int j = i - N5; b1p[j] = (j < L1N) ? b1[j] : 0.f; }
    }
}

// ---------------------------------------------------------------------------
// k1_xgemm: xg = concat(x)@W_ih^T + bias.
// M'=t*B+b ordering (81920 rows). BM=128, BN=512, BK=32, 512 thr, grid 640.
// 18 K-steps; per step: stage B(s+2) (4x global_load_lds/wave, wave-private
// tiles), issue x(s+2) (2 branchless float4 loads), MFMA step s from LDS,
// cvt+ds_write A(s+1), s_waitcnt vmcnt(6), raw s_barrier. Loads stay in
// flight across barriers (T4); vmcnt counts are exact by uniform issue.
// A garbage at k>=551 is annihilated by zero-packed W columns.
// ---------------------------------------------------------------------------
__device__ __forceinline__ float4 ld4u(const float* __restrict__ x1r,
                                       const float* __restrict__ x2r, int c)
{
    // branchless single-load: c<300 -> x1; else x2 (clamped into row for the
    // dead k>=552 pad region). One global_load_dwordx4 per call, always.
    int c2 = c - F1;
    c2 = (c2 < F2) ? c2 : 0;                  // pad region -> safe garbage
    const float* p = (c < F1) ? (x1r + c) : (x2r + c2);
    return *(const float4*)p;
}

__device__ __forceinline__ void k1_step(const short* __restrict__ Ab8,
                                        const short* __restrict__ Bb8,
                                        int w, int lane, f32x4 (&acc)[8][4])
{
    short8 a[8];
#pragma unroll
    for (int mt = 0; mt < 8; ++mt)
        a[mt] = *(const short8*)&Ab8[mt * 512 + lane * 8];
#pragma unroll
    for (int nt = 0; nt < 4; ++nt) {
        short8 b = *(const short8*)&Bb8[(w * 4 + nt) * 512 + lane * 8];
#pragma unroll
        for (int mt = 0; mt < 8; ++mt)
            acc[mt][nt] = MFMA(a[mt], b, acc[mt][nt]);
    }
}

__global__ __launch_bounds__(512, 2) void k1_xgemm(
    const float* __restrict__ x1, const float* __restrict__ x2,
    const short* __restrict__ Wihp, const float* __restrict__ biasg,
    short* __restrict__ xg)
{
    __shared__ __align__(16) short Ab[2][8][512];    // 16 KB: A-frag tiles
    __shared__ __align__(16) short Bb[3][32][512];   // 96 KB: B-frag tiles
    const int tid  = threadIdx.x;
    const int w    = tid >> 6;
    const int lane = tid & 63;
    const int c16  = lane & 15;
    const int kq   = lane >> 4;
    const int m0   = blockIdx.x * 128;      // m' = t*B + b; 128 | 16384
    const int t    = m0 >> 14;
    const int bb   = m0 & 16383;

    // A staging identity: wave w stages m-tile tm=w; lane covers
    // row = bb+w*16+c16, cols s*32 + kq*8 .. +8 (two float4 loads).
    const int arow = bb + w * 16 + c16;
    const float* x1r = x1 + ((size_t)arow * TT + t) * F1;
    const float* x2r = x2 + ((size_t)arow * TT + t) * F2;
    const int ac0 = kq * 8;

    f32x4 acc[8][4];
#pragma unroll
    for (int mt = 0; mt < 8; ++mt)
#pragma unroll
        for (int nt = 0; nt < 4; ++nt)
            acc[mt][nt] = (f32x4){0.f, 0.f, 0.f, 0.f};

    // ---- prologue: B(0),x(0),B(1),x(1); stage A(0); wait; barrier ----
#pragma unroll
    for (int i = 0; i < 4; ++i) {
        int tn = w * 4 + i;
        gload16(Wihp + ((tn * 18 + 0) << 9) + lane * 8, &Bb[0][tn][lane * 8]);
    }
    float4 p0 = ld4u(x1r, x2r, ac0), p1 = ld4u(x1r, x2r, ac0 + 4);
#pragma unroll
    for (int i = 0; i < 4; ++i) {
        int tn = w * 4 + i;
        gload16(Wihp + ((tn * 18 + 1) << 9) + lane * 8, &Bb[1][tn][lane * 8]);
    }
    float4 r0 = ld4u(x1r, x2r, 32 + ac0), r1 = ld4u(x1r, x2r, 32 + ac0 + 4);
    {   // cvt+write A(0)  (auto vmcnt wait for p0/p1: 6 younger in flight)
        short8 v;
        v[0]=f2bs(p0.x); v[1]=f2bs(p0.y); v[2]=f2bs(p0.z); v[3]=f2bs(p0.w);
        v[4]=f2bs(p1.x); v[5]=f2bs(p1.y); v[6]=f2bs(p1.z); v[7]=f2bs(p1.w);
        *(short8*)&Ab[0][w][lane * 8] = v;
    }
    WAITV(6); BAR(); MEMF();

    // ---- main loop: s = 0..15 (uniform 6 VMEM issues per iter) ----
    int bS = 2, bR = 0;                      // B stage/read buffer indices
    for (int s = 0; s < 16; ++s) {
        const int tk = s + 2;
#pragma unroll
        for (int i = 0; i < 4; ++i) {
            int tn = w * 4 + i;
            gload16(Wihp + ((tn * 18 + tk) << 9) + lane * 8, &Bb[bS][tn][lane * 8]);
        }
        int c = tk * 32 + ac0;
        float4 n0 = ld4u(x1r, x2r, c), n1 = ld4u(x1r, x2r, c + 4);

        k1_step(&Ab[s & 1][0][0], &Bb[bR][0][0], w, lane, acc);

        {   // cvt+write A(s+1) from r0/r1 = x(s+1)  (issued last iter)
            short8 v;
            v[0]=f2bs(r0.x); v[1]=f2bs(r0.y); v[2]=f2bs(r0.z); v[3]=f2bs(r0.w);
            v[4]=f2bs(r1.x); v[5]=f2bs(r1.y); v[6]=f2bs(r1.z); v[7]=f2bs(r1.w);
            *(short8*)&Ab[(s + 1) & 1][w][lane * 8] = v;
        }
        r0 = n0; r1 = n1;
        WAITV(6); BAR(); MEMF();
        bS = (bS == 2) ? 0 : bS + 1;
        bR = (bR == 2) ? 0 : bR + 1;
    }

    // ---- s = 16: no new issues; stage A(17); drain; barrier ----
    k1_step(&Ab[0][0][0], &Bb[1][0][0], w, lane, acc);
    {
        short8 v;
        v[0]=f2bs(r0.x); v[1]=f2bs(r0.y); v[2]=f2bs(r0.z); v[3]=f2bs(r0.w);
        v[4]=f2bs(r1.x); v[5]=f2bs(r1.y); v[6]=f2bs(r1.z); v[7]=f2bs(r1.w);
        *(short8*)&Ab[1][w][lane * 8] = v;
    }
    WAITV(0); BAR(); MEMF();

    // ---- s = 17 ----
    k1_step(&Ab[1][0][0], &Bb[2][0][0], w, lane, acc);

    // ---- epilogue: +bias, packed C-tile store (8B/lane, coalesced) ----
#pragma unroll
    for (int nt = 0; nt < 4; ++nt) {
        float bv = biasg[w * 64 + nt * 16 + c16];
#pragma unroll
        for (int mt = 0; mt < 8; ++mt) {
            short4v o;
#pragma unroll
            for (int r = 0; r < 4; ++r) o[r] = f2bs(acc[mt][nt][r] + bv);
            int tm = (m0 >> 4) + mt, tn = w * 4 + nt;
            *(short4v*)&xg[((tm * 32 + tn) << 8) + lane * 4] = o;
        }
    }
}

// ---------------------------------------------------------------------------
// k2_rec: fused LSTM recurrence, 32 samples/block, 512 blocks, 512 thr.
// W_hh B-frags in registers (reused all t). xg read as packed C-tiles (8B/lane).
// h round-trips through LDS; hs exported in packed A-tile layout (16B/lane).
// ---------------------------------------------------------------------------
__global__ __launch_bounds__(512, 2) void k2_rec(
    const short* __restrict__ Whhp, const short* __restrict__ xg,
    short* __restrict__ hs)
{
    __shared__ __align__(16) short hb[2][32][136];
    const int tid  = threadIdx.x;
    const int w    = tid >> 6;
    const int lane = tid & 63;
    const int quad = lane >> 4;
    const int c16  = lane & 15;
    const int btile = blockIdx.x * 2;       // sample-tile base (32 samples)

    short8 bfr[4][4];                       // [gate][ks]
#pragma unroll
    for (int g = 0; g < 4; ++g)
#pragma unroll
        for (int ks = 0; ks < 4; ++ks)
            bfr[g][ks] = *(const short8*)&Whhp[((((g * 8 + w) * 4) + ks) << 9) + lane * 8];

    float cst[2][4];
#pragma unroll
    for (int mt = 0; mt < 2; ++mt)
#pragma unroll
        for (int r = 0; r < 4; ++r) cst[mt][r] = 0.f;

    const int j = w * 16 + c16;

    for (int t = 0; t < TT; ++t) {
        // prefetch gate pre-activations (packed C-tiles)
        short4v xq[2][4];
#pragma unroll
        for (int mt = 0; mt < 2; ++mt)
#pragma unroll
            for (int g = 0; g < 4; ++g)
                xq[mt][g] = *(const short4v*)
                    &xg[((((t << 10) + btile + mt) * 32 + (g * 8 + w)) << 8) + lane * 4];

        f32x4 acc[2][4];
#pragma unroll
        for (int mt = 0; mt < 2; ++mt)
#pragma unroll
            for (int g = 0; g < 4; ++g)
                acc[mt][g] = (f32x4){0.f, 0.f, 0.f, 0.f};

        if (t > 0) {
            const short (*cur)[136] = hb[(t - 1) & 1];
#pragma unroll
            for (int ks = 0; ks < 4; ++ks) {
                short8 a[2];
#pragma unroll
                for (int mt = 0; mt < 2; ++mt)
                    a[mt] = *(const short8*)&cur[mt * 16 + c16][ks * 32 + quad * 8];
#pragma unroll
                for (int mt = 0; mt < 2; ++mt)
#pragma unroll
                    for (int g = 0; g < 4; ++g)
                        acc[mt][g] = MFMA(a[mt], bfr[g][ks], acc[mt][g]);
            }
        }

        short (*nxt)[136] = hb[t & 1];
#pragma unroll
        for (int mt = 0; mt < 2; ++mt) {
#pragma unroll
            for (int r = 0; r < 4; ++r) {
                int m = mt * 16 + quad * 4 + r;
                float gi = acc[mt][0][r] + b2f(xq[mt][0][r]);
                float gf = acc[mt][1][r] + b2f(xq[mt][1][r]);
                float gg = acc[mt][2][r] + b2f(xq[mt][2][r]);
                float go = acc[mt][3][r] + b2f(xq[mt][3][r]);
                float cn = sigf(gf) * cst[mt][r] + sigf(gi) * mytanh(gg);
                cst[mt][r] = cn;
                nxt[m][j] = f2bs(sigf(go) * mytanh(cn));
            }
        }
        __syncthreads();
        // export h_t in packed A-tile layout: wave w -> tile (tm=w>>2, kt=w&3)
        {
            int tm = w >> 2, kt = w & 3;
            short8 v = *(const short8*)&nxt[tm * 16 + c16][kt * 32 + quad * 8];
            *(short8*)&hs[(((btile + tm) * 20 + t * 4 + kt) << 9) + lane * 8] = v;
        }
    }
}

// ---------------------------------------------------------------------------
// mlp: fused 640->576(531)->256->64->2 + softmax. 32 samples/block, 256 thr.
// hs read as packed A-tiles; weights as packed B-tiles (all 16B/lane).
// ---------------------------------------------------------------------------
__global__ __launch_bounds__(256, 2) void mlp_kernel(
    const short* __restrict__ hs,
    const short* __restrict__ W1p, const float* __restrict__ b1p,
    const short* __restrict__ W2p, const float* __restrict__ b2,
    const short* __restrict__ W3p, const float* __restrict__ b3,
    const float* __restrict__ W4,  const float* __restrict__ b4,
    float* __restrict__ out)
{
    __shared__ __align__(16) short a1[32][584];
    __shared__ __align__(16) short a2[32][264];
    __shared__ __align__(16) short a3[32][72];
    const int tid  = threadIdx.x;
    const int w    = tid >> 6;
    const int lane = tid & 63;
    const int quad = lane >> 4;
    const int c16  = lane & 15;
    const int m0   = blockIdx.x * 32;
    const int mtile = blockIdx.x * 2;

    // ---- layer 1: K=640, N=576 (9 n-tiles per wave) ----
    {
        f32x4 acc[2][9];
#pragma unroll
        for (int mt = 0; mt < 2; ++mt)
#pragma unroll
            for (int i = 0; i < 9; ++i)
                acc[mt][i] = (f32x4){0.f, 0.f, 0.f, 0.f};
#pragma unroll 4
        for (int ks = 0; ks < 20; ++ks) {
            short8 a[2];
#pragma unroll
            for (int mt = 0; mt < 2; ++mt)
                a[mt] = *(const short8*)&hs[(((mtile + mt) * 20 + ks) << 9) + lane * 8];
#pragma unroll
            for (int i = 0; i < 9; ++i) {
                short8 b = *(const short8*)&W1p[(((w * 9 + i) * 20 + ks) << 9) + lane * 8];
                acc[0][i] = MFMA(a[0], b, acc[0][i]);
                acc[1][i] = MFMA(a[1], b, acc[1][i]);
            }
        }
#pragma unroll
        for (int i = 0; i < 9; ++i) {
            int n = (w * 9 + i) * 16 + c16;
            float bv = b1p[n];
#pragma unroll
            for (int mt = 0; mt < 2; ++mt)
#pragma unroll
                for (int r = 0; r < 4; ++r) {
                    int m = mt * 16 + quad * 4 + r;
                    float v = acc[mt][i][r] + bv;
                    a1[m][n] = f2bs(v > 0.f ? v : 0.f);
                }
        }
    }
    __syncthreads();

    // ---- layer 2: K=544, N=256 (4 n-tiles per wave) ----
    {
        f32x4 acc[2][4];
#pragma unroll
        for (int mt = 0; mt < 2; ++mt)
#pragma unroll
            for (int i = 0; i < 4; ++i)
                acc[mt][i] = (f32x4){0.f, 0.f, 0.f, 0.f};
#pragma unroll 4
        for (int ks = 0; ks < 17; ++ks) {
            short8 a[2];
#pragma unroll
            for (int mt = 0; mt < 2; ++mt)
                a[mt] = *(const short8*)&a1[mt * 16 + c16][ks * 32 + quad * 8];
#pragma unroll
            for (int i = 0; i < 4; ++i) {
                short8 b = *(const short8*)&W2p[(((w * 4 + i) * 17 + ks) << 9) + lane * 8];
                acc[0][i] = MFMA(a[0], b, acc[0][i]);
                acc[1][i] = MFMA(a[1], b, acc[1][i]);
            }
        }
#pragma unroll
        for (int i = 0; i < 4; ++i) {
            int n = (w * 4 + i) * 16 + c16;
            float bv = b2[n];
#pragma unroll
            for (int mt = 0; mt < 2; ++mt)
#pragma unroll
                for (int r = 0; r < 4; ++r) {
                    int m = mt * 16 + quad * 4 + r;
                    float v = acc[mt][i][r] + bv;
                    a2[m][n] = f2bs(v > 0.f ? v : 0.f);
                }
        }
    }
    __syncthreads();

    // ---- layer 3: K=256, N=64 (1 n-tile per wave) ----
    {
        f32x4 acc[2];
        acc[0] = (f32x4){0.f, 0.f, 0.f, 0.f};
        acc[1] = (f32x4){0.f, 0.f, 0.f, 0.f};
#pragma unroll
        for (int ks = 0; ks < 8; ++ks) {
            short8 a[2];
#pragma unroll
            for (int mt = 0; mt < 2; ++mt)
                a[mt] = *(const short8*)&a2[mt * 16 + c16][ks * 32 + quad * 8];
            short8 b = *(const short8*)&W3p[((w * 8 + ks) << 9) + lane * 8];
            acc[0] = MFMA(a[0], b, acc[0]);
            acc[1] = MFMA(a[1], b, acc[1]);
        }
        int n = w * 16 + c16;
        float bv = b3[n];
#pragma unroll
        for (int mt = 0; mt < 2; ++mt)
#pragma unroll
            for (int r = 0; r < 4; ++r) {
                int m = mt * 16 + quad * 4 + r;
                float v = acc[mt][r] + bv;
                a3[m][n] = f2bs(v > 0.f ? v : 0.f);
            }
    }
    __syncthreads();

    // ---- layer 4 + softmax on wave 0 ----
    if (tid < 64) {
        int m   = tid >> 1;
        int cls = tid & 1;
        float s = b4[cls];
#pragma unroll 8
        for (int k = 0; k < 64; ++k)
            s += b2f(a3[m][k]) * W4[cls * 64 + k];
        float other = __shfl_xor(s, 1);
        float p = 1.f / (1.f + __expf(other - s));
        out[(m0 + m) * 2 + cls] = p;
    }
}

// ---------------------------------------------------------------------------
extern "C" void kernel_launch(void* const* d_in, const int* in_sizes, int n_in,
                              void* d_out, int out_size, void* d_ws, size_t ws_size,
                              hipStream_t stream)
{
    (void)in_sizes; (void)n_in; (void)out_size;
    if (ws_size < (size_t)WS_NEED) return;

    const float* x1   = (const float*)d_in[0];
    const float* x2   = (const float*)d_in[1];
    const float* W_ih = (const float*)d_in[2];
    const float* W_hh = (const float*)d_in[3];
    const float* b_ih = (const float*)d_in[4];
    const float* b_hh = (const float*)d_in[5];
    const float* W1   = (const float*)d_in[6];
    const float* b1   = (const float*)d_in[7];
    const float* W2   = (const float*)d_in[8];
    const float* b2   = (const float*)d_in[9];
    const float* W3   = (const float*)d_in[10];
    const float* b3   = (const float*)d_in[11];
    const float* W4   = (const float*)d_in[12];
    const float* b4   = (const float*)d_in[13];

    char* ws = (char*)d_ws;
    short* Wihp  = (short*)(ws + O_WIH);
    short* Whhp  = (short*)(ws + O_WHH);
    short* W1p   = (short*)(ws + O_W1);
    short* W2p   = (short*)(ws + O_W2);
    short* W3p   = (short*)(ws + O_W3);
    float* biasg = (float*)(ws + O_BG);
    float* b1p   = (float*)(ws + O_B1);
    short* xg    = (short*)(ws + O_XG);
    short* hsb   = (short*)(ws + O_HS);

    prep_kernel<<<3461, 256, 0, stream>>>(W_ih, W_hh, b_ih, b_hh, W1, b1, W2, W3,
                                          Wihp, Whhp, biasg, W1p, b1p, W2p, W3p);
    k1_xgemm<<<640, 512, 0, stream>>>(x1, x2, Wihp, biasg, xg);
    k2_rec<<<512, 512, 0, stream>>>(Whhp, xg, hsb);
    mlp_kernel<<<512, 256, 0, stream>>>(hsb, W1p, b1p, W2p, b2, W3p, b3, W4, b4,
                                        (float*)d_out);
}